// Round 2
// baseline (129.531 us; speedup 1.0000x reference)
//
#include <hip/hip_runtime.h>

// GATv2 layer, N=1024 nodes, C=256 channels. Flash-fused: no NxN score
// matrix is materialized. ws usage: 2 MB + 256 B only.
//
// ws layout (floats):
//   [0]                  dtype flag (int: 1 = bf16 inputs, 0 = f32 inputs)
//   [64,      262208)    g_src   1024x256 f32
//   [262208,  524352)    g_tgt   1024x256 f32

typedef unsigned short u16;
typedef unsigned int   u32;

#define NNODE 1024
#define NC    256
#define NEG   0.2f

__device__ __forceinline__ float bf2f(u16 h) {
    u32 u = ((u32)h) << 16;
    return __builtin_bit_cast(float, u);
}
__device__ __forceinline__ u16 f2bf(float f) {
    u32 u = __builtin_bit_cast(u32, f);
    u32 r = (u + 0x7FFFu + ((u >> 16) & 1u)) >> 16;   // round-nearest-even
    return (u16)r;
}

// ---------------------------------------------------------------------------
// K0: dtype detect. Interpret first 256 u16 of `nodes` as bf16; count values
// whose exponent is implausible for N(0,1) data. True bf16 -> ~0 outliers.
// f32 data read as u16 pairs -> ~100+ outliers (mantissa-garbage halves).
// ---------------------------------------------------------------------------
__global__ void detect_kernel(const u16* __restrict__ nodes, int* __restrict__ flag)
{
    const int lane = threadIdx.x;             // 64 threads
    ushort4 v = *(const ushort4*)(nodes + lane * 4);
    const u16 h[4] = {v.x, v.y, v.z, v.w};
    int cnt = 0;
    #pragma unroll
    for (int q = 0; q < 4; ++q) {
        int e = (h[q] >> 7) & 0xFF;
        cnt += (e >= 132 || (e >= 1 && e <= 90)) ? 1 : 0;
    }
    #pragma unroll
    for (int off = 32; off; off >>= 1) cnt += __shfl_xor(cnt, off, 64);
    if (lane == 0) *flag = (cnt >= 64) ? 0 : 1;
}

// ---------------------------------------------------------------------------
// K1: g_src / g_tgt = nodes @ W^T + b   (f32 out; bf16 or f32 in, per flag)
// grid (8, 32): x = ct (0..3 src cols, 4..7 tgt cols), y = i-tile of 32 rows
// ---------------------------------------------------------------------------
__global__ __launch_bounds__(256) void lin_kernel(
    const void* __restrict__ nodes_v,
    const void* __restrict__ Wsrc_v, const void* __restrict__ bsrc_v,
    const void* __restrict__ Wtgt_v, const void* __restrict__ btgt_v,
    const int* __restrict__ flag,
    float* __restrict__ gsrc, float* __restrict__ gtgt)
{
    __shared__ float nT[64][34];   // [k][i]
    __shared__ float wT[64][68];   // [k][c]

    const int bf = *flag;
    const int t  = threadIdx.x;
    const int ct = blockIdx.x;
    const int it = blockIdx.y;
    const int i0 = it * 32;
    const bool is_src = (ct < 4);
    const int c0 = (is_src ? ct : ct - 4) * 64;
    const void* __restrict__ Wv = is_src ? Wsrc_v : Wtgt_v;
    const void* __restrict__ bv = is_src ? bsrc_v : btgt_v;
    float* __restrict__ g       = is_src ? gsrc : gtgt;

    const int tc = t & 15, ti = t >> 4;
    float acc[2][4] = {};

    for (int k0 = 0; k0 < NC; k0 += 64) {
        __syncthreads();
        {   // stage nodes tile [32 i][64 k] -> nT[k][i]
            int ii = t & 31, kg = t >> 5;                    // kg 0..7
            float vals[8];
            if (bf) {
                uint4 v = *(const uint4*)((const u16*)nodes_v + (i0 + ii) * NC + k0 + kg * 8);
                const u16* pv = (const u16*)&v;
                #pragma unroll
                for (int q = 0; q < 8; ++q) vals[q] = bf2f(pv[q]);
            } else {
                const float* nf = (const float*)nodes_v;
                float4 v0 = *(const float4*)(nf + (i0 + ii) * NC + k0 + kg * 8);
                float4 v1 = *(const float4*)(nf + (i0 + ii) * NC + k0 + kg * 8 + 4);
                vals[0] = v0.x; vals[1] = v0.y; vals[2] = v0.z; vals[3] = v0.w;
                vals[4] = v1.x; vals[5] = v1.y; vals[6] = v1.z; vals[7] = v1.w;
            }
            #pragma unroll
            for (int q = 0; q < 8; ++q) nT[kg * 8 + q][ii] = vals[q];
        }
        {   // stage W tile [64 c][64 k] -> wT[k][c]
            int cc = t & 63, kg = t >> 6;                    // kg 0..3
            float vals[16];
            if (bf) {
                const u16* W = (const u16*)Wv;
                uint4 v0 = *(const uint4*)(W + (c0 + cc) * NC + k0 + kg * 16);
                uint4 v1 = *(const uint4*)(W + (c0 + cc) * NC + k0 + kg * 16 + 8);
                const u16* p0 = (const u16*)&v0;
                const u16* p1 = (const u16*)&v1;
                #pragma unroll
                for (int q = 0; q < 8; ++q) { vals[q] = bf2f(p0[q]); vals[8 + q] = bf2f(p1[q]); }
            } else {
                const float* W = (const float*)Wv;
                #pragma unroll
                for (int h = 0; h < 4; ++h) {
                    float4 v = *(const float4*)(W + (c0 + cc) * NC + k0 + kg * 16 + 4 * h);
                    vals[4 * h + 0] = v.x; vals[4 * h + 1] = v.y;
                    vals[4 * h + 2] = v.z; vals[4 * h + 3] = v.w;
                }
            }
            #pragma unroll
            for (int q = 0; q < 16; ++q) wT[kg * 16 + q][cc] = vals[q];
        }
        __syncthreads();
        #pragma unroll 8
        for (int kk = 0; kk < 64; ++kk) {
            float2 av = *(const float2*)&nT[kk][2 * ti];
            float4 bvv = *(const float4*)&wT[kk][4 * tc];
            float sa[2] = {av.x, av.y};
            float tb[4] = {bvv.x, bvv.y, bvv.z, bvv.w};
            #pragma unroll
            for (int a = 0; a < 2; ++a)
                #pragma unroll
                for (int b = 0; b < 4; ++b)
                    acc[a][b] = fmaf(sa[a], tb[b], acc[a][b]);
        }
    }

    float bb[4];
    #pragma unroll
    for (int q = 0; q < 4; ++q)
        bb[q] = bf ? bf2f(((const u16*)bv)[c0 + 4 * tc + q])
                   : ((const float*)bv)[c0 + 4 * tc + q];
    #pragma unroll
    for (int a = 0; a < 2; ++a) {
        int i = i0 + 2 * ti + a;
        float4 o = make_float4(acc[a][0] + bb[0], acc[a][1] + bb[1],
                               acc[a][2] + bb[2], acc[a][3] + bb[3]);
        *(float4*)(g + i * NC + c0 + 4 * tc) = o;
    }
}

// ---------------------------------------------------------------------------
// K2: fused score + online softmax + PV. Block owns 4 i-rows (wave = row).
// Loop over 16 j-tiles of 64. No score matrix in global memory.
// LDS pad 257: score reads gt[lane][c] bank=(lane+c)%32 conflict-free;
//              PV reads gt[j][lane+64k] bank=(j+lane)%32 conflict-free.
// ---------------------------------------------------------------------------
__global__ __launch_bounds__(256) void fused_kernel(
    const float* __restrict__ gsrc, const float* __restrict__ gtgt,
    const void* __restrict__ aw_v, const int* __restrict__ adj,
    const int* __restrict__ flag, void* __restrict__ out_v)
{
    __shared__ float  gt[64][257];
    __shared__ float2 agl[4][NC];     // (g_src val, a val) per block-row
    __shared__ float  p_lds[4][64];

    const int bf   = *flag;
    const int t    = threadIdx.x;
    const int b    = blockIdx.x;      // rows 4b..4b+3
    const int i    = t >> 6;          // wave id = local row
    const int lane = t & 63;
    const int row  = 4 * b + i;

    {   // stage (g_src, a) interleaved; wave-local (row i written+read by wave i)
        float4 g4 = *(const float4*)(gsrc + row * NC + lane * 4);
        float av[4];
        if (bf) {
            ushort4 a4 = *(const ushort4*)((const u16*)aw_v + lane * 4);
            av[0] = bf2f(a4.x); av[1] = bf2f(a4.y); av[2] = bf2f(a4.z); av[3] = bf2f(a4.w);
        } else {
            float4 a4 = *(const float4*)((const float*)aw_v + lane * 4);
            av[0] = a4.x; av[1] = a4.y; av[2] = a4.z; av[3] = a4.w;
        }
        agl[i][lane * 4 + 0] = make_float2(g4.x, av[0]);
        agl[i][lane * 4 + 1] = make_float2(g4.y, av[1]);
        agl[i][lane * 4 + 2] = make_float2(g4.z, av[2]);
        agl[i][lane * 4 + 3] = make_float2(g4.w, av[3]);
    }

    float m = -1e30f, l = 0.f;
    float o0 = 0.f, o1 = 0.f, o2 = 0.f, o3 = 0.f;   // c = lane + {0,64,128,192}

    for (int j0 = 0; j0 < NNODE; j0 += 64) {
        __syncthreads();              // prev tile's PV done before restage
        for (int r = i; r < 64; r += 4) {   // wave i stages rows i, i+4, ...
            float4 v = *(const float4*)(gtgt + (j0 + r) * NC + lane * 4);
            gt[r][lane * 4 + 0] = v.x;
            gt[r][lane * 4 + 1] = v.y;
            gt[r][lane * 4 + 2] = v.z;
            gt[r][lane * 4 + 3] = v.w;
        }
        __syncthreads();

        const int valid = adj[row * NNODE + j0 + lane];

        // score: s = sum_c a[c] * lrelu(gs[i][c] + gt[lane][c])
        float s0 = 0.f, s1 = 0.f, s2 = 0.f, s3 = 0.f;
        #pragma unroll 4
        for (int c = 0; c < NC; c += 4) {
            float2 ag0 = agl[i][c + 0];
            float2 ag1 = agl[i][c + 1];
            float2 ag2 = agl[i][c + 2];
            float2 ag3 = agl[i][c + 3];
            float y0 = ag0.x + gt[lane][c + 0];
            float y1 = ag1.x + gt[lane][c + 1];
            float y2 = ag2.x + gt[lane][c + 2];
            float y3 = ag3.x + gt[lane][c + 3];
            s0 = fmaf(ag0.y, fmaxf(y0, NEG * y0), s0);
            s1 = fmaf(ag1.y, fmaxf(y1, NEG * y1), s1);
            s2 = fmaf(ag2.y, fmaxf(y2, NEG * y2), s2);
            s3 = fmaf(ag3.y, fmaxf(y3, NEG * y3), s3);
        }
        const float s = (s0 + s1) + (s2 + s3);

        // online softmax, wave = row. Mask applied at p (not via -inf in exp):
        // all-masked tile keeps m unchanged, p=0, alpha=1 -> harmless.
        float sm = valid ? s : -1e30f;
        float tmax = sm;
        #pragma unroll
        for (int off = 32; off; off >>= 1)
            tmax = fmaxf(tmax, __shfl_xor(tmax, off, 64));
        const float mn    = fmaxf(m, tmax);
        const float alpha = __expf(m - mn);          // exp(-1e30-x) -> 0, no NaN
        const float p     = valid ? __expf(s - mn) : 0.f;
        float ps = p;
        #pragma unroll
        for (int off = 32; off; off >>= 1) ps += __shfl_xor(ps, off, 64);
        l = l * alpha + ps;
        m = mn;
        p_lds[i][lane] = p;           // wave-local: no barrier needed

        o0 *= alpha; o1 *= alpha; o2 *= alpha; o3 *= alpha;
        #pragma unroll 8
        for (int j = 0; j < 64; ++j) {
            float w = p_lds[i][j];
            o0 = fmaf(w, gt[j][lane      ], o0);
            o1 = fmaf(w, gt[j][lane +  64], o1);
            o2 = fmaf(w, gt[j][lane + 128], o2);
            o3 = fmaf(w, gt[j][lane + 192], o3);
        }
    }

    const float inv = 1.0f / l;       // every row has a self-loop -> l > 0
    if (bf) {
        u16* out = (u16*)out_v;
        out[row * NC + lane      ] = f2bf(o0 * inv);
        out[row * NC + lane +  64] = f2bf(o1 * inv);
        out[row * NC + lane + 128] = f2bf(o2 * inv);
        out[row * NC + lane + 192] = f2bf(o3 * inv);
    } else {
        float* out = (float*)out_v;
        out[row * NC + lane      ] = o0 * inv;
        out[row * NC + lane +  64] = o1 * inv;
        out[row * NC + lane + 128] = o2 * inv;
        out[row * NC + lane + 192] = o3 * inv;
    }
}

extern "C" void kernel_launch(void* const* d_in, const int* in_sizes, int n_in,
                              void* d_out, int out_size, void* d_ws, size_t ws_size,
                              hipStream_t stream)
{
    const int* adj = (const int*)d_in[1];

    int*   flag = (int*)d_ws;
    float* gsrc = (float*)d_ws + 64;
    float* gtgt = (float*)d_ws + 64 + NNODE * NC;

    detect_kernel<<<1, 64, 0, stream>>>((const u16*)d_in[0], flag);
    lin_kernel<<<dim3(8, 32), 256, 0, stream>>>(d_in[0], d_in[2], d_in[3],
                                                d_in[4], d_in[5], flag, gsrc, gtgt);
    fused_kernel<<<256, 256, 0, stream>>>(gsrc, gtgt, d_in[6], adj, flag, d_out);
}

// Round 5
// 112.551 us; speedup vs baseline: 1.1509x; 1.1509x over previous
//
#include <hip/hip_runtime.h>

// GATv2 layer, N=1024 nodes, C=256 channels. Flash-fused.
// Dtype-ADAPTIVE (round-2 mechanism, the only version that ever passed):
// detect_kernel probes whether device float tensors are bf16 or f32; every
// input load and output store branches on the flag (wave-uniform).
// Perf deltas vs round 2: j-split across blockIdx.y (occupancy) + gt pad 260
// (aligned b128 staging, bank-conflict fix).
//
// ws layout (floats):
//   [0, 64)                        flag (int, idx 0)
//   [64,      64+262144)           g_src f32
//   [...,     +262144)             g_tgt f32
//   [...,     +NS*262144)          po  partial O [NS][1024][256]
//   next NS*1024                   pm  partial max per (z,row)
//   next NS*1024                   pls partial denom per (z,row)

typedef unsigned short u16;
typedef unsigned int   u32;

#define NNODE 1024
#define NC    256
#define NEG   0.2f

__device__ __forceinline__ float bf2f(u16 h) {
    u32 u = ((u32)h) << 16;
    return __builtin_bit_cast(float, u);
}
__device__ __forceinline__ u16 f2bf(float f) {
    u32 u = __builtin_bit_cast(u32, f);
    u32 r = (u + 0x7FFFu + ((u >> 16) & 1u)) >> 16;   // round-nearest-even
    return (u16)r;
}

// ---------------------------------------------------------------------------
// K0: dtype detect (round-2 verbatim). First 256 u16 of nodes as bf16:
// N(0,1) bf16 -> ~0 implausible exponents; f32 read as u16 pairs -> ~107.
// ---------------------------------------------------------------------------
__global__ void detect_kernel(const u16* __restrict__ nodes, int* __restrict__ flag)
{
    const int lane = threadIdx.x;             // 64 threads
    ushort4 v = *(const ushort4*)(nodes + lane * 4);
    const u16 h[4] = {v.x, v.y, v.z, v.w};
    int cnt = 0;
    #pragma unroll
    for (int q = 0; q < 4; ++q) {
        int e = (h[q] >> 7) & 0xFF;
        cnt += (e >= 132 || (e >= 1 && e <= 90)) ? 1 : 0;
    }
    #pragma unroll
    for (int off = 32; off; off >>= 1) cnt += __shfl_xor(cnt, off, 64);
    if (lane == 0) *flag = (cnt >= 64) ? 0 : 1;
}

// ---------------------------------------------------------------------------
// K1: g_src / g_tgt = nodes @ W^T + b (round-2 verbatim, flag-driven loads)
// grid (8, 32): x = ct (0..3 src c-tiles, 4..7 tgt), y = 32-row i-tile.
// ---------------------------------------------------------------------------
__global__ __launch_bounds__(256) void lin_kernel(
    const void* __restrict__ nodes_v,
    const void* __restrict__ Wsrc_v, const void* __restrict__ bsrc_v,
    const void* __restrict__ Wtgt_v, const void* __restrict__ btgt_v,
    const int* __restrict__ flag,
    float* __restrict__ gsrc, float* __restrict__ gtgt)
{
    __shared__ float nT[64][34];   // [k][i]
    __shared__ float wT[64][68];   // [k][c]

    const int bf = *flag;
    const int t  = threadIdx.x;
    const int ct = blockIdx.x;
    const int it = blockIdx.y;
    const int i0 = it * 32;
    const bool is_src = (ct < 4);
    const int c0 = (is_src ? ct : ct - 4) * 64;
    const void* __restrict__ Wv = is_src ? Wsrc_v : Wtgt_v;
    const void* __restrict__ bv = is_src ? bsrc_v : btgt_v;
    float* __restrict__ g       = is_src ? gsrc : gtgt;

    const int tc = t & 15, ti = t >> 4;
    float acc[2][4] = {};

    for (int k0 = 0; k0 < NC; k0 += 64) {
        __syncthreads();
        {   // stage nodes tile [32 i][64 k] -> nT[k][i]
            int ii = t & 31, kg = t >> 5;                    // kg 0..7
            float vals[8];
            if (bf) {
                uint4 v = *(const uint4*)((const u16*)nodes_v + (i0 + ii) * NC + k0 + kg * 8);
                const u16* pv = (const u16*)&v;
                #pragma unroll
                for (int q = 0; q < 8; ++q) vals[q] = bf2f(pv[q]);
            } else {
                const float* nf = (const float*)nodes_v;
                float4 v0 = *(const float4*)(nf + (i0 + ii) * NC + k0 + kg * 8);
                float4 v1 = *(const float4*)(nf + (i0 + ii) * NC + k0 + kg * 8 + 4);
                vals[0] = v0.x; vals[1] = v0.y; vals[2] = v0.z; vals[3] = v0.w;
                vals[4] = v1.x; vals[5] = v1.y; vals[6] = v1.z; vals[7] = v1.w;
            }
            #pragma unroll
            for (int q = 0; q < 8; ++q) nT[kg * 8 + q][ii] = vals[q];
        }
        {   // stage W tile [64 c][64 k] -> wT[k][c]
            int cc = t & 63, kg = t >> 6;                    // kg 0..3
            float vals[16];
            if (bf) {
                const u16* W = (const u16*)Wv;
                uint4 v0 = *(const uint4*)(W + (c0 + cc) * NC + k0 + kg * 16);
                uint4 v1 = *(const uint4*)(W + (c0 + cc) * NC + k0 + kg * 16 + 8);
                const u16* p0 = (const u16*)&v0;
                const u16* p1 = (const u16*)&v1;
                #pragma unroll
                for (int q = 0; q < 8; ++q) { vals[q] = bf2f(p0[q]); vals[8 + q] = bf2f(p1[q]); }
            } else {
                const float* W = (const float*)Wv;
                #pragma unroll
                for (int h = 0; h < 4; ++h) {
                    float4 v = *(const float4*)(W + (c0 + cc) * NC + k0 + kg * 16 + 4 * h);
                    vals[4 * h + 0] = v.x; vals[4 * h + 1] = v.y;
                    vals[4 * h + 2] = v.z; vals[4 * h + 3] = v.w;
                }
            }
            #pragma unroll
            for (int q = 0; q < 16; ++q) wT[kg * 16 + q][cc] = vals[q];
        }
        __syncthreads();
        #pragma unroll 8
        for (int kk = 0; kk < 64; ++kk) {
            float2 av = *(const float2*)&nT[kk][2 * ti];
            float4 bvv = *(const float4*)&wT[kk][4 * tc];
            float sa[2] = {av.x, av.y};
            float tb[4] = {bvv.x, bvv.y, bvv.z, bvv.w};
            #pragma unroll
            for (int a = 0; a < 2; ++a)
                #pragma unroll
                for (int b = 0; b < 4; ++b)
                    acc[a][b] = fmaf(sa[a], tb[b], acc[a][b]);
        }
    }

    float bb[4];
    #pragma unroll
    for (int q = 0; q < 4; ++q)
        bb[q] = bf ? bf2f(((const u16*)bv)[c0 + 4 * tc + q])
                   : ((const float*)bv)[c0 + 4 * tc + q];
    #pragma unroll
    for (int a = 0; a < 2; ++a) {
        int i = i0 + 2 * ti + a;
        float4 o = make_float4(acc[a][0] + bb[0], acc[a][1] + bb[1],
                               acc[a][2] + bb[2], acc[a][3] + bb[3]);
        *(float4*)(g + i * NC + c0 + 4 * tc) = o;
    }
}

// ---------------------------------------------------------------------------
// K2: fused score + online softmax + PV over j in [z*jcnt, (z+1)*jcnt).
// 256 threads, 4 waves, wave = local row (round-2 verified structure).
// gt pad 260: 16B-aligned rows -> aligned b128 staging.
// ---------------------------------------------------------------------------
__global__ __launch_bounds__(256) void fused_kernel(
    const float* __restrict__ gsrc, const float* __restrict__ gtgt,
    const void* __restrict__ aw_v, const int* __restrict__ adj,
    const int* __restrict__ flag, int jcnt,
    float* __restrict__ po, float* __restrict__ pm,
    float* __restrict__ pls, void* __restrict__ out_v)
{
    __shared__ float  gt[64][260];
    __shared__ float2 agl[4][NC];     // (g_src val, a val) per block-row
    __shared__ float  p_lds[4][64];

    const int bf   = *flag;
    const int t    = threadIdx.x;
    const int i    = t >> 6;          // wave id = local row
    const int lane = t & 63;
    const int row  = blockIdx.x * 4 + i;
    const int z    = blockIdx.y;
    const int jbase = z * jcnt;

    {   // stage (g_src, a); wave-local (row i written+read only by wave i)
        float4 g4 = *(const float4*)(gsrc + row * NC + lane * 4);
        float av[4];
        if (bf) {
            ushort4 a4 = *(const ushort4*)((const u16*)aw_v + lane * 4);
            av[0] = bf2f(a4.x); av[1] = bf2f(a4.y); av[2] = bf2f(a4.z); av[3] = bf2f(a4.w);
        } else {
            float4 a4 = *(const float4*)((const float*)aw_v + lane * 4);
            av[0] = a4.x; av[1] = a4.y; av[2] = a4.z; av[3] = a4.w;
        }
        agl[i][lane * 4 + 0] = make_float2(g4.x, av[0]);
        agl[i][lane * 4 + 1] = make_float2(g4.y, av[1]);
        agl[i][lane * 4 + 2] = make_float2(g4.z, av[2]);
        agl[i][lane * 4 + 3] = make_float2(g4.w, av[3]);
    }

    float m = -1e30f, l = 0.f;
    float o0 = 0.f, o1 = 0.f, o2 = 0.f, o3 = 0.f;   // c = lane + {0,64,128,192}

    for (int j0 = jbase; j0 < jbase + jcnt; j0 += 64) {
        __syncthreads();              // prev tile's PV reads of gt done
        for (int r = i; r < 64; r += 4) {   // wave i stages rows i, i+4, ...
            float4 v = *(const float4*)(gtgt + (j0 + r) * NC + lane * 4);
            *(float4*)&gt[r][lane * 4] = v;           // aligned b128
        }
        __syncthreads();

        const int valid = adj[row * NNODE + j0 + lane];

        // score: s = sum_c a[c] * lrelu(gs[i][c] + gt[lane][c])
        float s0 = 0.f, s1 = 0.f, s2 = 0.f, s3 = 0.f;
        #pragma unroll 4
        for (int c = 0; c < NC; c += 4) {
            float4 ag01 = *(const float4*)&agl[i][c];      // g0,a0,g1,a1
            float4 ag23 = *(const float4*)&agl[i][c + 2];  // g2,a2,g3,a3
            float4 gv   = *(const float4*)&gt[lane][c];
            float y0 = ag01.x + gv.x;
            float y1 = ag01.z + gv.y;
            float y2 = ag23.x + gv.z;
            float y3 = ag23.z + gv.w;
            s0 = fmaf(ag01.y, fmaxf(y0, NEG * y0), s0);
            s1 = fmaf(ag01.w, fmaxf(y1, NEG * y1), s1);
            s2 = fmaf(ag23.y, fmaxf(y2, NEG * y2), s2);
            s3 = fmaf(ag23.w, fmaxf(y3, NEG * y3), s3);
        }
        const float s = (s0 + s1) + (s2 + s3);

        // online softmax, wave = row. Mask at p: all-masked tile -> p=0,
        // alpha=1, m unchanged -> harmless.
        float sm = valid ? s : -1e30f;
        float tmax = sm;
        #pragma unroll
        for (int off = 32; off; off >>= 1)
            tmax = fmaxf(tmax, __shfl_xor(tmax, off, 64));
        const float mn    = fmaxf(m, tmax);
        const float alpha = __expf(m - mn);          // exp of <=0, no NaN
        const float p     = valid ? __expf(s - mn) : 0.f;
        float ps = p;
        #pragma unroll
        for (int off = 32; off; off >>= 1) ps += __shfl_xor(ps, off, 64);
        l = l * alpha + ps;
        m = mn;
        p_lds[i][lane] = p;           // wave-local producer/consumer

        o0 *= alpha; o1 *= alpha; o2 *= alpha; o3 *= alpha;
        #pragma unroll 8
        for (int j = 0; j < 64; ++j) {
            float w = p_lds[i][j];
            o0 = fmaf(w, gt[j][lane      ], o0);
            o1 = fmaf(w, gt[j][lane +  64], o1);
            o2 = fmaf(w, gt[j][lane + 128], o2);
            o3 = fmaf(w, gt[j][lane + 192], o3);
        }
    }

    if (out_v) {                      // NS == 1 direct path
        const float inv = 1.0f / l;   // self-loop guarantees l > 0
        if (bf) {
            u16* out = (u16*)out_v;
            out[row * NC + lane      ] = f2bf(o0 * inv);
            out[row * NC + lane +  64] = f2bf(o1 * inv);
            out[row * NC + lane + 128] = f2bf(o2 * inv);
            out[row * NC + lane + 192] = f2bf(o3 * inv);
        } else {
            float* out = (float*)out_v;
            out[row * NC + lane      ] = o0 * inv;
            out[row * NC + lane +  64] = o1 * inv;
            out[row * NC + lane + 128] = o2 * inv;
            out[row * NC + lane + 192] = o3 * inv;
        }
    } else {                          // partial path
        float* p = po + (size_t)(z * NNODE + row) * NC;
        p[lane      ] = o0;
        p[lane +  64] = o1;
        p[lane + 128] = o2;
        p[lane + 192] = o3;
        if (lane == 0) {
            pm [z * NNODE + row] = m;
            pls[z * NNODE + row] = l;
        }
    }
}

// ---------------------------------------------------------------------------
// K3: merge NS partials per row. Empty chunks (m=-1e30,l=0,o=0) contribute 0.
// grid 1024 blocks (row) x 256 threads (channel).
// ---------------------------------------------------------------------------
__global__ __launch_bounds__(256) void combine_kernel(
    const float* __restrict__ po, const float* __restrict__ pm,
    const float* __restrict__ pls, const int* __restrict__ flag,
    int ns, void* __restrict__ out_v)
{
    const int bf  = *flag;
    const int row = blockIdx.x;
    const int c   = threadIdx.x;

    float mstar = -1e30f;
    for (int zz = 0; zz < ns; ++zz)
        mstar = fmaxf(mstar, pm[zz * NNODE + row]);

    float acc = 0.f, lsum = 0.f;
    for (int zz = 0; zz < ns; ++zz) {
        const float wz = __expf(pm[zz * NNODE + row] - mstar);
        lsum = fmaf(pls[zz * NNODE + row], wz, lsum);
        acc  = fmaf(po[(size_t)(zz * NNODE + row) * NC + c], wz, acc);
    }
    const float v = acc / lsum;
    if (bf) ((u16*)out_v)[row * NC + c] = f2bf(v);
    else    ((float*)out_v)[row * NC + c] = v;
}

extern "C" void kernel_launch(void* const* d_in, const int* in_sizes, int n_in,
                              void* d_out, int out_size, void* d_ws, size_t ws_size,
                              hipStream_t stream)
{
    const int* adj = (const int*)d_in[1];

    int*   flag = (int*)d_ws;
    float* gsrc = (float*)d_ws + 64;
    float* gtgt = gsrc + NNODE * NC;

    detect_kernel<<<1, 64, 0, stream>>>((const u16*)d_in[0], flag);
    lin_kernel<<<dim3(8, 32), 256, 0, stream>>>(d_in[0], d_in[2], d_in[3],
                                                d_in[4], d_in[5], flag, gsrc, gtgt);

    const size_t base = 64ull + 2ull * NNODE * NC;
    int NS = 0;
    {
        size_t need4 = (base + 4ull * NNODE * NC + 8ull * NNODE) * 4ull;
        size_t need2 = (base + 2ull * NNODE * NC + 4ull * NNODE) * 4ull;
        if      (ws_size >= need4) NS = 4;
        else if (ws_size >= need2) NS = 2;
    }

    if (NS) {
        float* po  = gtgt + NNODE * NC;
        float* pm  = po + (size_t)NS * NNODE * NC;
        float* pls = pm + (size_t)NS * NNODE;
        fused_kernel<<<dim3(256, NS), 256, 0, stream>>>(
            gsrc, gtgt, d_in[6], adj, flag, NNODE / NS, po, pm, pls, nullptr);
        combine_kernel<<<NNODE, 256, 0, stream>>>(po, pm, pls, flag, NS, d_out);
    } else {
        fused_kernel<<<dim3(256, 1), 256, 0, stream>>>(
            gsrc, gtgt, d_in[6], adj, flag, NNODE, nullptr, nullptr, nullptr, d_out);
    }
}

// Round 6
// 68.438 us; speedup vs baseline: 1.8927x; 1.6446x over previous
//
#include <hip/hip_runtime.h>

// GATv2 layer, N=1024 nodes, C=256 channels. Flash-fused, dtype-adaptive
// (flag: 1 = device float tensors are bf16, 0 = f32 — f32 observed).
// v3: f16-packed LDS + g_src in registers + packed-f16 score math + wide PV.
//
// ws layout (bytes):
//   [0,   256)        flag (int at 0)
//   [256, +512K)      gsh  g_src as f16  [1024][256]
//   [...,+512K)       gth  g_tgt as f16  [1024][256]
//   [...,+NS*1M)      po   partial O f32 [NS][1024][256]
//   next NS*4K        pm   partial max per (z,row)
//   next NS*4K        pls  partial denom per (z,row)

typedef unsigned short u16;
typedef unsigned int   u32;
typedef _Float16 h2 __attribute__((ext_vector_type(2)));

#define NNODE 1024
#define NC    256
#define NEG   0.2f

__device__ __forceinline__ float bf2f(u16 h) {
    u32 u = ((u32)h) << 16;
    return __builtin_bit_cast(float, u);
}
__device__ __forceinline__ u16 f2bf(float f) {
    u32 u = __builtin_bit_cast(u32, f);
    u32 r = (u + 0x7FFFu + ((u >> 16) & 1u)) >> 16;   // RNE
    return (u16)r;
}
__device__ __forceinline__ u16 f2h(float f) {
    _Float16 h = (_Float16)f;                         // RNE
    return __builtin_bit_cast(u16, h);
}
__device__ __forceinline__ h2 bch(u32 u) { return __builtin_bit_cast(h2, u); }

__device__ __forceinline__ h2 lrelu2(h2 y) {
    h2 yn = y * (_Float16)NEG;
#if __has_builtin(__builtin_elementwise_max)
    return __builtin_elementwise_max(y, yn);
#else
    h2 r; r.x = y.x > yn.x ? y.x : yn.x; r.y = y.y > yn.y ? y.y : yn.y;
    return r;
#endif
}
__device__ __forceinline__ float dot2(h2 a, h2 b, float acc) {
#if __has_builtin(__builtin_amdgcn_fdot2)
    return __builtin_amdgcn_fdot2(a, b, acc, false);
#else
    acc = fmaf((float)a.x, (float)b.x, acc);
    return fmaf((float)a.y, (float)b.y, acc);
#endif
}

// ---------------------------------------------------------------------------
// K0: dtype detect (verified). bf16 N(0,1) -> ~0 outlier exponents; f32 read
// as u16 pairs -> ~half outliers.
// ---------------------------------------------------------------------------
__global__ void detect_kernel(const u16* __restrict__ nodes, int* __restrict__ flag)
{
    const int lane = threadIdx.x;             // 64 threads
    ushort4 v = *(const ushort4*)(nodes + lane * 4);
    const u16 h[4] = {v.x, v.y, v.z, v.w};
    int cnt = 0;
    #pragma unroll
    for (int q = 0; q < 4; ++q) {
        int e = (h[q] >> 7) & 0xFF;
        cnt += (e >= 132 || (e >= 1 && e <= 90)) ? 1 : 0;
    }
    #pragma unroll
    for (int off = 32; off; off >>= 1) cnt += __shfl_xor(cnt, off, 64);
    if (lane == 0) *flag = (cnt >= 64) ? 0 : 1;
}

// ---------------------------------------------------------------------------
// K1: g = nodes @ W^T + b, output packed f16 (gsh / gth). Round-5 body
// (verified) with f16 epilogue. grid (8, 32), 256 threads.
// ---------------------------------------------------------------------------
__global__ __launch_bounds__(256) void lin_kernel(
    const void* __restrict__ nodes_v,
    const void* __restrict__ Wsrc_v, const void* __restrict__ bsrc_v,
    const void* __restrict__ Wtgt_v, const void* __restrict__ btgt_v,
    const int* __restrict__ flag,
    u16* __restrict__ gsh, u16* __restrict__ gth)
{
    __shared__ float nT[64][34];   // [k][i]
    __shared__ float wT[64][68];   // [k][c]

    const int bf = *flag;
    const int t  = threadIdx.x;
    const int ct = blockIdx.x;
    const int it = blockIdx.y;
    const int i0 = it * 32;
    const bool is_src = (ct < 4);
    const int c0 = (is_src ? ct : ct - 4) * 64;
    const void* __restrict__ Wv = is_src ? Wsrc_v : Wtgt_v;
    const void* __restrict__ bv = is_src ? bsrc_v : btgt_v;
    u16* __restrict__ g         = is_src ? gsh : gth;

    const int tc = t & 15, ti = t >> 4;
    float acc[2][4] = {};

    for (int k0 = 0; k0 < NC; k0 += 64) {
        __syncthreads();
        {   // stage nodes tile [32 i][64 k] -> nT[k][i]
            int ii = t & 31, kg = t >> 5;
            float vals[8];
            if (bf) {
                uint4 v = *(const uint4*)((const u16*)nodes_v + (i0 + ii) * NC + k0 + kg * 8);
                const u16* pv = (const u16*)&v;
                #pragma unroll
                for (int q = 0; q < 8; ++q) vals[q] = bf2f(pv[q]);
            } else {
                const float* nf = (const float*)nodes_v;
                float4 v0 = *(const float4*)(nf + (i0 + ii) * NC + k0 + kg * 8);
                float4 v1 = *(const float4*)(nf + (i0 + ii) * NC + k0 + kg * 8 + 4);
                vals[0] = v0.x; vals[1] = v0.y; vals[2] = v0.z; vals[3] = v0.w;
                vals[4] = v1.x; vals[5] = v1.y; vals[6] = v1.z; vals[7] = v1.w;
            }
            #pragma unroll
            for (int q = 0; q < 8; ++q) nT[kg * 8 + q][ii] = vals[q];
        }
        {   // stage W tile [64 c][64 k] -> wT[k][c]
            int cc = t & 63, kg = t >> 6;
            float vals[16];
            if (bf) {
                const u16* W = (const u16*)Wv;
                uint4 v0 = *(const uint4*)(W + (c0 + cc) * NC + k0 + kg * 16);
                uint4 v1 = *(const uint4*)(W + (c0 + cc) * NC + k0 + kg * 16 + 8);
                const u16* p0 = (const u16*)&v0;
                const u16* p1 = (const u16*)&v1;
                #pragma unroll
                for (int q = 0; q < 8; ++q) { vals[q] = bf2f(p0[q]); vals[8 + q] = bf2f(p1[q]); }
            } else {
                const float* W = (const float*)Wv;
                #pragma unroll
                for (int h = 0; h < 4; ++h) {
                    float4 v = *(const float4*)(W + (c0 + cc) * NC + k0 + kg * 16 + 4 * h);
                    vals[4 * h + 0] = v.x; vals[4 * h + 1] = v.y;
                    vals[4 * h + 2] = v.z; vals[4 * h + 3] = v.w;
                }
            }
            #pragma unroll
            for (int q = 0; q < 16; ++q) wT[kg * 16 + q][cc] = vals[q];
        }
        __syncthreads();
        #pragma unroll 8
        for (int kk = 0; kk < 64; ++kk) {
            float2 av = *(const float2*)&nT[kk][2 * ti];
            float4 bvv = *(const float4*)&wT[kk][4 * tc];
            float sa[2] = {av.x, av.y};
            float tb[4] = {bvv.x, bvv.y, bvv.z, bvv.w};
            #pragma unroll
            for (int a = 0; a < 2; ++a)
                #pragma unroll
                for (int b = 0; b < 4; ++b)
                    acc[a][b] = fmaf(sa[a], tb[b], acc[a][b]);
        }
    }

    float bb[4];
    #pragma unroll
    for (int q = 0; q < 4; ++q)
        bb[q] = bf ? bf2f(((const u16*)bv)[c0 + 4 * tc + q])
                   : ((const float*)bv)[c0 + 4 * tc + q];
    #pragma unroll
    for (int a = 0; a < 2; ++a) {
        int irow = i0 + 2 * ti + a;
        ushort4 ov;
        ov.x = f2h(acc[a][0] + bb[0]);
        ov.y = f2h(acc[a][1] + bb[1]);
        ov.z = f2h(acc[a][2] + bb[2]);
        ov.w = f2h(acc[a][3] + bb[3]);
        *(ushort4*)(g + (size_t)irow * NC + c0 + 4 * tc) = ov;
    }
}

// ---------------------------------------------------------------------------
// K2: fused score + online softmax + PV, f16 LDS.
// 256 threads, 4 waves, wave = local row. Per j-tile of 64:
//  score: lane = (q = lane>>4 channel-quarter, jl = lane&15); g_src quarter
//         lives in 32 VGPRs; 4 passes of 16 j; partial over 64 ch; reduce
//         over q via shfl_xor(16,32); select s for j = lane.
//  softmax: verified round-5 block (wave = row).
//  PV: lane = (oc = lane&31 channel-octet, hh = lane>>5 j-parity); per 2 j
//      one b128 gt read (8 ch) + one p broadcast; f32 accumulate.
// gt32 pad 132: all b128 access 2-way bank max (free).
// ---------------------------------------------------------------------------
__global__ __launch_bounds__(256, 4) void fused_kernel(
    const u16* __restrict__ gsh, const u16* __restrict__ gth,
    const void* __restrict__ aw_v, const int* __restrict__ adj,
    const int* __restrict__ flag, int jcnt,
    float* __restrict__ po, float* __restrict__ pm,
    float* __restrict__ pls, void* __restrict__ out_v)
{
    __shared__ u32  gt32[64][132];    // [j][chalf] f16x2, 33.8 KB
    __shared__ u32  gs32[4][128];     // [row][chalf] f16x2
    __shared__ u32  a32[128];         // [chalf] f16x2
    __shared__ float p_lds[4][64];

    const int bf   = *flag;
    const int t    = threadIdx.x;
    const int i    = t >> 6;          // wave id = local row
    const int lane = t & 63;
    const int row  = blockIdx.x * 4 + i;
    const int z    = blockIdx.y;
    const int jbase = z * jcnt;
    const int jl = lane & 15, q  = lane >> 4;   // score layout
    const int oc = lane & 31, hh = lane >> 5;   // PV layout

    {   // stage g_src row (f16 from gsh): lane covers 4 ch
        uint2 v = *(const uint2*)(gsh + (size_t)row * NC + lane * 4);
        *(uint2*)&gs32[i][2 * lane] = v;
    }
    if (t < 128) {                    // stage a as f16x2 (flag-converted)
        float a0, a1;
        if (bf) { a0 = bf2f(((const u16*)aw_v)[2 * t]); a1 = bf2f(((const u16*)aw_v)[2 * t + 1]); }
        else    { a0 = ((const float*)aw_v)[2 * t];     a1 = ((const float*)aw_v)[2 * t + 1]; }
        h2 av; av.x = (_Float16)a0; av.y = (_Float16)a1;
        a32[t] = __builtin_bit_cast(u32, av);
    }
    __syncthreads();

    // g_src quarter (64 ch) into registers: 32 x h2
    h2 gsr[32];
    #pragma unroll
    for (int k = 0; k < 8; ++k) {
        uint4 gv = *(const uint4*)&gs32[i][q * 32 + 4 * k];
        gsr[4 * k + 0] = bch(gv.x); gsr[4 * k + 1] = bch(gv.y);
        gsr[4 * k + 2] = bch(gv.z); gsr[4 * k + 3] = bch(gv.w);
    }

    float m = -1e30f, l = 0.f;
    float of[8] = {0.f, 0.f, 0.f, 0.f, 0.f, 0.f, 0.f, 0.f};  // ch 8*oc..8*oc+7

    for (int j0 = jbase; j0 < jbase + jcnt; j0 += 64) {
        __syncthreads();              // prev tile's PV reads done
        {   // stage gt tile f16: thread r = t&63, seg = t>>6 (64 ch)
            int r = t & 63, seg = t >> 6;
            const u16* src = gth + (size_t)(j0 + r) * NC + seg * 64;
            #pragma unroll
            for (int k = 0; k < 8; ++k) {
                uint4 v = *(const uint4*)(src + 8 * k);
                *(uint4*)&gt32[r][seg * 32 + 4 * k] = v;
            }
        }
        __syncthreads();

        // ---- score: 4 passes x 16 j, per-lane 64-ch partial ----
        float spv[4] = {0.f, 0.f, 0.f, 0.f};
        #pragma unroll
        for (int k = 0; k < 8; ++k) {
            uint4 a4 = *(const uint4*)&a32[q * 32 + 4 * k];
            h2 a0 = bch(a4.x), a1 = bch(a4.y), a2 = bch(a4.z), a3 = bch(a4.w);
            h2 g0 = gsr[4 * k], g1 = gsr[4 * k + 1],
               g2 = gsr[4 * k + 2], g3 = gsr[4 * k + 3];
            #pragma unroll
            for (int p = 0; p < 4; ++p) {
                uint4 g4 = *(const uint4*)&gt32[16 * p + jl][q * 32 + 4 * k];
                spv[p] = dot2(a0, lrelu2(g0 + bch(g4.x)), spv[p]);
                spv[p] = dot2(a1, lrelu2(g1 + bch(g4.y)), spv[p]);
                spv[p] = dot2(a2, lrelu2(g2 + bch(g4.z)), spv[p]);
                spv[p] = dot2(a3, lrelu2(g3 + bch(g4.w)), spv[p]);
            }
        }
        #pragma unroll
        for (int p = 0; p < 4; ++p) {   // reduce over q (lane bits 4,5)
            spv[p] += __shfl_xor(spv[p], 16, 64);
            spv[p] += __shfl_xor(spv[p], 32, 64);
        }
        // j = j0 + lane: score held in spv[lane>>4]
        const float s = (lane < 16) ? spv[0] : (lane < 32) ? spv[1]
                      : (lane < 48) ? spv[2] : spv[3];

        // ---- online softmax (verified block), wave = row ----
        const int valid = adj[row * NNODE + j0 + lane];
        float sm = valid ? s : -1e30f;
        float tmax = sm;
        #pragma unroll
        for (int off = 32; off; off >>= 1)
            tmax = fmaxf(tmax, __shfl_xor(tmax, off, 64));
        const float mn    = fmaxf(m, tmax);
        const float alpha = __expf(m - mn);
        const float p     = valid ? __expf(s - mn) : 0.f;
        float ps = p;
        #pragma unroll
        for (int off = 32; off; off >>= 1) ps += __shfl_xor(ps, off, 64);
        l = l * alpha + ps;
        m = mn;
        p_lds[i][lane] = p;           // wave-local producer/consumer

        // ---- PV: per 2 j one b128 (8 ch) + one p broadcast ----
        #pragma unroll
        for (int k = 0; k < 8; ++k) of[k] *= alpha;
        #pragma unroll 8
        for (int jp = 0; jp < 32; ++jp) {
            const float w = p_lds[i][2 * jp + hh];
            uint4 g4 = *(const uint4*)&gt32[2 * jp + hh][4 * oc];
            h2 v0 = bch(g4.x), v1 = bch(g4.y), v2 = bch(g4.z), v3 = bch(g4.w);
            of[0] = fmaf(w, (float)v0.x, of[0]);
            of[1] = fmaf(w, (float)v0.y, of[1]);
            of[2] = fmaf(w, (float)v1.x, of[2]);
            of[3] = fmaf(w, (float)v1.y, of[3]);
            of[4] = fmaf(w, (float)v2.x, of[4]);
            of[5] = fmaf(w, (float)v2.y, of[5]);
            of[6] = fmaf(w, (float)v3.x, of[6]);
            of[7] = fmaf(w, (float)v3.y, of[7]);
        }
    }

    // combine the two j-parity halves: ch 8*oc+k total in all lanes
    #pragma unroll
    for (int k = 0; k < 8; ++k) of[k] += __shfl_xor(of[k], 32, 64);

    if (lane < 32) {
        if (out_v) {                  // NS == 1 direct path
            const float inv = 1.0f / l;   // self-loop -> l > 0
            if (bf) {
                u16* out = (u16*)out_v;
                ushort4 oa, ob;
                oa.x = f2bf(of[0] * inv); oa.y = f2bf(of[1] * inv);
                oa.z = f2bf(of[2] * inv); oa.w = f2bf(of[3] * inv);
                ob.x = f2bf(of[4] * inv); ob.y = f2bf(of[5] * inv);
                ob.z = f2bf(of[6] * inv); ob.w = f2bf(of[7] * inv);
                *(ushort4*)(out + (size_t)row * NC + 8 * oc)     = oa;
                *(ushort4*)(out + (size_t)row * NC + 8 * oc + 4) = ob;
            } else {
                float* out = (float*)out_v;
                *(float4*)(out + (size_t)row * NC + 8 * oc) =
                    make_float4(of[0] * inv, of[1] * inv, of[2] * inv, of[3] * inv);
                *(float4*)(out + (size_t)row * NC + 8 * oc + 4) =
                    make_float4(of[4] * inv, of[5] * inv, of[6] * inv, of[7] * inv);
            }
        } else {                      // partial path
            float* pp = po + ((size_t)z * NNODE + row) * NC + 8 * oc;
            *(float4*)pp       = make_float4(of[0], of[1], of[2], of[3]);
            *(float4*)(pp + 4) = make_float4(of[4], of[5], of[6], of[7]);
        }
    }
    if (!out_v && lane == 0) {
        pm [z * NNODE + row] = m;
        pls[z * NNODE + row] = l;
    }
}

// ---------------------------------------------------------------------------
// K3: merge NS partials per row (verified). Empty chunks contribute 0.
// ---------------------------------------------------------------------------
__global__ __launch_bounds__(256) void combine_kernel(
    const float* __restrict__ po, const float* __restrict__ pm,
    const float* __restrict__ pls, const int* __restrict__ flag,
    int ns, void* __restrict__ out_v)
{
    const int bf  = *flag;
    const int row = blockIdx.x;
    const int c   = threadIdx.x;

    float mstar = -1e30f;
    for (int zz = 0; zz < ns; ++zz)
        mstar = fmaxf(mstar, pm[zz * NNODE + row]);

    float acc = 0.f, lsum = 0.f;
    for (int zz = 0; zz < ns; ++zz) {
        const float wz = __expf(pm[zz * NNODE + row] - mstar);
        lsum = fmaf(pls[zz * NNODE + row], wz, lsum);
        acc  = fmaf(po[(size_t)(zz * NNODE + row) * NC + c], wz, acc);
    }
    const float v = acc / lsum;
    if (bf) ((u16*)out_v)[row * NC + c] = f2bf(v);
    else    ((float*)out_v)[row * NC + c] = v;
}

extern "C" void kernel_launch(void* const* d_in, const int* in_sizes, int n_in,
                              void* d_out, int out_size, void* d_ws, size_t ws_size,
                              hipStream_t stream)
{
    const int* adj = (const int*)d_in[1];

    char* wsb = (char*)d_ws;
    int* flag = (int*)wsb;
    u16* gsh  = (u16*)(wsb + 256);
    u16* gth  = gsh + (size_t)NNODE * NC;

    detect_kernel<<<1, 64, 0, stream>>>((const u16*)d_in[0], flag);
    lin_kernel<<<dim3(8, 32), 256, 0, stream>>>(d_in[0], d_in[2], d_in[3],
                                                d_in[4], d_in[5], flag, gsh, gth);

    const size_t base = 256 + 2ull * NNODE * NC * sizeof(u16);   // flag + gsh + gth
    int NS = 0;
    {
        size_t need4 = base + (4ull * NNODE * NC + 8ull * NNODE) * 4ull;
        size_t need2 = base + (2ull * NNODE * NC + 4ull * NNODE) * 4ull;
        if      (ws_size >= need4) NS = 4;
        else if (ws_size >= need2) NS = 2;
    }

    if (NS) {
        float* po  = (float*)(wsb + base);
        float* pm  = po + (size_t)NS * NNODE * NC;
        float* pls = pm + (size_t)NS * NNODE;
        fused_kernel<<<dim3(256, NS), 256, 0, stream>>>(
            gsh, gth, d_in[6], adj, flag, NNODE / NS, po, pm, pls, nullptr);
        combine_kernel<<<NNODE, 256, 0, stream>>>(po, pm, pls, flag, NS, d_out);
    } else {
        fused_kernel<<<dim3(256, 1), 256, 0, stream>>>(
            gsh, gth, d_in[6], adj, flag, NNODE, nullptr, nullptr, nullptr, d_out);
    }
}